// Round 8
// baseline (1246.156 us; speedup 1.0000x reference)
//
#include <hip/hip_runtime.h>
#include <hip/hip_fp16.h>

// RGCN block-decomposition, fully fused: per-edge transform + packed-f16
// atomic scatter-add into PLANE-SPREAD accumulator. No sort phase.
//
// Round-7 null (paired emission, SMEM edge loads: no change) killed the
// instruction-issue theory. New theory: same-line RMW serialization at TCC —
// an edge's 64 channels hit only 2-4 cache lines in row-major acc. This
// round: acc becomes 32 channel-planes of [num_nodes] half2; one wave-atomic
// now touches 64 distinct lines spread across TCC channels.

#define DIM 64
#define NBLK 8
#define BS 8
#define NREL 8
#define COL_PAD 12                                  // 8 -> 12 floats row pad
#define LDS_T_TOTAL (NREL * NBLK * BS * COL_PAD)    // 6144 floats = 24 KiB

typedef unsigned int uint32;

// Hoist all loads for edge slot i; edge index forced to SGPR -> s_load.
#define PRE(i, e_)                                                          \
    const int   eu##i = __builtin_amdgcn_readfirstlane(e_);                 \
    const int   s##i  = src[eu##i];                                         \
    const int   t##i  = tgt[eu##i];                                         \
    const int   r##i  = etype[eu##i];                                       \
    const float w##i  = ew[eu##i];                                          \
    const float4* xs##i = (const float4*)(x + (size_t)s##i * DIM + b * BS); \
    const float4 v0_##i = xs##i[0];                                         \
    const float4 v1_##i = xs##i[1];                                         \
    const float* bp##i = bcol + r##i * (NBLK * BS * COL_PAD);               \
    const float4 c0_##i = *(const float4*)bp##i;                            \
    const float4 c1_##i = *(const float4*)(bp##i + 4);

#define VAL(i)                                                              \
    const float val##i = w##i *                                             \
        (v0_##i.x * c0_##i.x + v0_##i.y * c0_##i.y +                        \
         v0_##i.z * c0_##i.z + v0_##i.w * c0_##i.w +                        \
         v1_##i.x * c1_##i.x + v1_##i.y * c1_##i.y +                        \
         v1_##i.z * c1_##i.z + v1_##i.w * c1_##i.w);

// Paired emission into plane-spread layout: plane pk (= lane>>1) at node tt.
// Even lanes carry edge a's channels (lane,lane+1); odd lanes edge b's
// (lane-1,lane). 64 lanes -> 64 distinct cache lines (2 nodes x 32 planes).
#define EMIT_PAIR(a, b_)                                                    \
    {                                                                       \
        const float dn = __shfl_down(val##a, 1, 64);                        \
        const float up = __shfl_up(val##b_, 1, 64);                         \
        const __half2 h = even ? __floats2half2_rn(val##a, dn)              \
                               : __floats2half2_rn(up, val##b_);            \
        const int tt = even ? t##a : t##b_;                                 \
        unsafeAtomicAdd(&acc[(size_t)pk * num_nodes + tt], h);              \
    }

// ---- Main fused kernel ------------------------------------------------------
__global__ __launch_bounds__(512) void rgcn_pk_kernel(
    const float* __restrict__ x,
    const float* __restrict__ blocks,
    const float* __restrict__ ew,
    const int* __restrict__ src,
    const int* __restrict__ tgt,
    const int* __restrict__ etype,
    __half2* __restrict__ acc,         // 32 planes of [num_nodes] half2
    int num_nodes,
    int num_edges)
{
    __shared__ float blkT[LDS_T_TOTAL];
    // blkT[((r*8+b)*8 + o)*12 + i] = blocks[r][b][i][o]; per-lane column read
    // is 2x ds_read_b128 at 48B stride -> 2 lanes/bank (0 conflicts measured).
    for (int l = threadIdx.x; l < NREL * NBLK * BS * BS; l += blockDim.x) {
        const int o = l & 7;
        const int i = (l >> 3) & 7;
        const int rb = l >> 6;
        blkT[(rb * 8 + o) * COL_PAD + i] = blocks[l];
    }
    __syncthreads();

    const int lane = threadIdx.x & 63;
    const int wid  = __builtin_amdgcn_readfirstlane(threadIdx.x >> 6);
    const int wave = blockIdx.x * 8 + wid;             // blockDim == 512
    const int W    = gridDim.x * 8;                    // total waves

    const int b  = lane >> 3;   // which 8x8 block
    const int oo = lane & 7;    // output channel within block
    const float* bcol = &blkT[(b * 8 + oo) * COL_PAD];
    const bool even = (lane & 1) == 0;
    const int  pk   = lane >> 1;                       // channel-pair plane

    int e = wave;
    // 4 independent edges in flight: e, e+W, e+2W, e+3W.
    for (; e + 3 * W < num_edges; e += 4 * W) {
        PRE(0, e) PRE(1, e + W) PRE(2, e + 2 * W) PRE(3, e + 3 * W)
        VAL(0) VAL(1) VAL(2) VAL(3)
        EMIT_PAIR(0, 1)
        EMIT_PAIR(2, 3)
    }
    for (; e < num_edges; e += W) {     // per-wave tail (<=3 strides)
        PRE(0, e)
        VAL(0)
        const float dn = __shfl_down(val0, 1, 64);
        if (even)
            unsafeAtomicAdd(&acc[(size_t)pk * num_nodes + t0],
                            __floats2half2_rn(val0, dn));
    }
}

// ---- Convert: plane-spread f16 acc -> row-major f32 out (LDS transpose) -----
// One wave per 64-node tile. Reads plane-contiguous (coalesced), transposes
// through LDS (stride 65 -> 2-way bank alias max), writes out rows coalesced.
__global__ __launch_bounds__(64) void convert_kernel(
    const __half2* __restrict__ acc, float* __restrict__ out, int num_nodes)
{
    __shared__ float lds[64 * 65];
    const int lane = threadIdx.x;
    const int n0   = blockIdx.x * 64;
    const int n    = n0 + lane;

#pragma unroll
    for (int p = 0; p < 32; ++p) {
        __half2 h = (n < num_nodes) ? acc[(size_t)p * num_nodes + n]
                                    : __half2{};
        const float2 f = __half22float2(h);
        lds[lane * 65 + 2 * p]     = f.x;
        lds[lane * 65 + 2 * p + 1] = f.y;
    }
    __syncthreads();   // single wave; cheap, guarantees LDS visibility

#pragma unroll 8
    for (int row = 0; row < 64; ++row) {
        if (n0 + row < num_nodes)
            out[(size_t)(n0 + row) * 64 + lane] = lds[row * 65 + lane];
    }
}

// ---- Fallback (ws too small): f32-atomic fused kernel (round-1 proven) ------
#define LDS_BLK_STRIDE 72
#define LDS_REL_STRIDE (NBLK * LDS_BLK_STRIDE)
#define LDS_TOTAL (NREL * LDS_REL_STRIDE)

__global__ __launch_bounds__(256) void rgcn_edge_kernel(
    const float* __restrict__ x, const float* __restrict__ blocks,
    const float* __restrict__ ew, const int* __restrict__ src,
    const int* __restrict__ tgt, const int* __restrict__ etype,
    float* __restrict__ out, int num_edges)
{
    __shared__ float blk[LDS_TOTAL];
    for (int l = threadIdx.x; l < NREL * NBLK * BS * BS; l += blockDim.x) {
        int r = l >> 9, bb = (l >> 6) & 7, rest = l & 63;
        blk[r * LDS_REL_STRIDE + bb * LDS_BLK_STRIDE + rest] = blocks[l];
    }
    __syncthreads();
    const int lane = threadIdx.x & 63;
    const int wave = blockIdx.x * (blockDim.x >> 6) + (threadIdx.x >> 6);
    const int total_waves = gridDim.x * (blockDim.x >> 6);
    const int b = lane >> 3;
    for (int e = wave; e < num_edges; e += total_waves) {
        const int s = src[e], t = tgt[e], r = etype[e];
        const float w = ew[e];
        const float4* xs = reinterpret_cast<const float4*>(x + (size_t)s * DIM + b * BS);
        const float4 v0 = xs[0], v1 = xs[1];
        const float* bb = &blk[r * LDS_REL_STRIDE + b * LDS_BLK_STRIDE + (lane & 7)];
        float a = v0.x * bb[0] + v0.y * bb[BS] + v0.z * bb[2 * BS] + v0.w * bb[3 * BS]
                + v1.x * bb[4 * BS] + v1.y * bb[5 * BS] + v1.z * bb[6 * BS] + v1.w * bb[7 * BS];
        atomicAdd(&out[(size_t)t * DIM + lane], w * a);
    }
}

extern "C" void kernel_launch(void* const* d_in, const int* in_sizes, int n_in,
                              void* d_out, int out_size, void* d_ws, size_t ws_size,
                              hipStream_t stream) {
    const float* x      = (const float*)d_in[0];
    const float* blocks = (const float*)d_in[1];
    const float* ew     = (const float*)d_in[2];
    const int*   src    = (const int*)d_in[3];
    const int*   tgt    = (const int*)d_in[4];
    const int*   etype  = (const int*)d_in[5];
    float* out = (float*)d_out;

    const int num_edges = in_sizes[2];
    const int num_nodes = in_sizes[0] / DIM;

    const size_t acc_b = (size_t)num_nodes * DIM * sizeof(__half);  // 6.4 MB

    if (ws_size < acc_b) {   // fallback: f32 atomics straight into d_out
        hipMemsetAsync(d_out, 0, (size_t)out_size * sizeof(float), stream);
        rgcn_edge_kernel<<<2048, 256, 0, stream>>>(
            x, blocks, ew, src, tgt, etype, out, num_edges);
        return;
    }

    __half2* acc = (__half2*)d_ws;

    // f16 accumulator must start at zero every call.
    hipMemsetAsync(acc, 0, acc_b, stream);

    rgcn_pk_kernel<<<1024, 512, 0, stream>>>(
        x, blocks, ew, src, tgt, etype, acc, num_nodes, num_edges);

    const int nblocks = (num_nodes + 63) / 64;
    convert_kernel<<<nblocks, 64, 0, stream>>>(acc, out, num_nodes);
}

// Round 9
// 539.115 us; speedup vs baseline: 2.3115x; 2.3115x over previous
//
#include <hip/hip_runtime.h>

// RGCN block-decomposition: bucketed counting sort + per-bucket LDS f32
// aggregation. ZERO global atomics on the math path.
//
// R8 falsified line-spreading (write-amp 8x, 10x slower); R1/5/6/7 pinned the
// device-scope atomic path at ~115us regardless of op count/packing. So:
// sum-before-multiply (reference order), with segment sums in LDS.
//
//   1. histA:   per-4096-edge tile histogram of bucket = tgt>>6  (LDS hist)
//   2. colscan: exclusive prefix over tiles per bucket (tile_hist in place)
//   3. scan_totals: exclusive scan of bucket totals -> bbase[nb+1]
//   4. scatterB: LDS-cursor scatter of packed {w|tl|r|s} u64 payloads into
//                bucket-sorted order (write window = nb hot regions only)
//   5. rgcn_agg_kernel: one block per bucket. agg[8r][64n][64ch] f32 in LDS
//      (128KB). Per edge: s_load payload + coalesced 256B x row + ds_add.
//      Post-pass: out = sum_r B_r * agg_r, single coalesced store. Exact f32.

#define DIM 64
#define NBLK 8
#define BS 8
#define NREL 8
#define COL_PAD 12                                  // 8 -> 12 floats row pad
#define LDS_T_TOTAL (NREL * NBLK * BS * COL_PAD)    // 6144 floats = 24 KiB

#define TILE 4096      // edges per sort tile
#define MAXB 1024      // max buckets supported by LDS hist/cursor arrays
#define NW 8           // waves per 512-thread block

typedef unsigned int uint32;
typedef unsigned long long uint64;

// ---- 1. per-tile bucket histogram -------------------------------------------
__global__ __launch_bounds__(512) void histA(
    const int* __restrict__ tgt, uint32* __restrict__ tile_hist,
    int num_edges, int nb)
{
    __shared__ uint32 h[MAXB];
    for (int i = threadIdx.x; i < nb; i += 512) h[i] = 0u;
    __syncthreads();
    const int base = blockIdx.x * TILE;
    const int end  = min(base + TILE, num_edges);
    for (int j = base + (int)threadIdx.x; j < end; j += 512)
        atomicAdd(&h[tgt[j] >> 6], 1u);
    __syncthreads();
    uint32* dst = tile_hist + (size_t)blockIdx.x * nb;
    for (int i = threadIdx.x; i < nb; i += 512) dst[i] = h[i];
}

// ---- 2. per-bucket exclusive prefix over tiles (in place) + totals ----------
__global__ __launch_bounds__(64) void colscan(
    uint32* __restrict__ tile_hist, uint32* __restrict__ totals,
    int nt, int nb)
{
    const int b    = blockIdx.x;
    const int lane = threadIdx.x;
    uint32 carry = 0;
    for (int t0 = 0; t0 < nt; t0 += 64) {
        const int t = t0 + lane;
        uint32 v = (t < nt) ? tile_hist[(size_t)t * nb + b] : 0u;
        uint32 xin = v;
#pragma unroll
        for (int d = 1; d < 64; d <<= 1) {
            uint32 tm = __shfl_up(xin, d, 64);
            if (lane >= d) xin += tm;
        }
        if (t < nt) tile_hist[(size_t)t * nb + b] = carry + xin - v;
        carry += __shfl(xin, 63, 64);
    }
    if (lane == 0) totals[b] = carry;
}

// ---- 3. exclusive scan of bucket totals -> bbase[0..nb] ---------------------
__global__ __launch_bounds__(512) void scan_totals(
    const uint32* __restrict__ totals, uint32* __restrict__ bbase, int nb)
{
    __shared__ uint32 wtot[8];
    const int tid = threadIdx.x, lane = tid & 63, wid = tid >> 6;
    uint32 carry = 0;
    const int nch = (nb + 511) >> 9;
    for (int c = 0; c < nch; ++c) {
        const int idx = (c << 9) + tid;
        uint32 v = (idx < nb) ? totals[idx] : 0u;
        uint32 xin = v;
#pragma unroll
        for (int d = 1; d < 64; d <<= 1) {
            uint32 t = __shfl_up(xin, d, 64);
            if (lane >= d) xin += t;
        }
        if (lane == 63) wtot[wid] = xin;
        __syncthreads();
        if (wid == 0) {
            uint32 y = (lane < 8) ? wtot[lane] : 0u;
#pragma unroll
            for (int d = 1; d < 8; d <<= 1) {
                uint32 t = __shfl_up(y, d, 64);
                if (lane >= d) y += t;
            }
            if (lane < 8) wtot[lane] = y;
        }
        __syncthreads();
        const uint32 base = carry + ((wid > 0) ? wtot[wid - 1] : 0u);
        if (idx < nb) bbase[idx] = base + xin - v;
        carry += wtot[7];
        __syncthreads();
    }
    if (tid == 0) bbase[nb] = carry;
}

// ---- 4. scatter packed payloads into bucket-sorted order --------------------
__global__ __launch_bounds__(512) void scatterB(
    const int* __restrict__ src, const int* __restrict__ tgt,
    const int* __restrict__ etype, const float* __restrict__ ew,
    const uint32* __restrict__ tile_hist, const uint32* __restrict__ bbase,
    uint64* __restrict__ payload, int num_edges, int nb)
{
    __shared__ uint32 cur[MAXB];
    const uint32* th = tile_hist + (size_t)blockIdx.x * nb;
    for (int i = threadIdx.x; i < nb; i += 512) cur[i] = bbase[i] + th[i];
    __syncthreads();
    const int base = blockIdx.x * TILE;
    const int end  = min(base + TILE, num_edges);
    for (int j = base + (int)threadIdx.x; j < end; j += 512) {
        const int t = tgt[j];
        const uint32 pos = atomicAdd(&cur[t >> 6], 1u);
        // lo: s[0:15] | r[16:18] | tlocal[19:24]
        const uint32 lo = (uint32)src[j] | ((uint32)etype[j] << 16)
                        | ((uint32)(t & 63) << 19);
        payload[pos] = ((uint64)__float_as_uint(ew[j]) << 32) | lo;
    }
}

// ---- 5. per-bucket LDS aggregation + block-diag multiply --------------------
// Edge slot i: payload via wave-uniform s_load; one f32 of x per lane.
#define PREA(i, j_)                                                         \
    const int    ju##i = __builtin_amdgcn_readfirstlane(j_);                \
    const uint64 p##i  = payload[ju##i];                                    \
    const uint32 lo##i = (uint32)p##i;                                      \
    const float  w##i  = __uint_as_float((uint32)(p##i >> 32));             \
    const float  xv##i = x[((size_t)(lo##i & 0xFFFFu) << 6) + lane];

#define EMITA(i)                                                            \
    atomicAdd(&agg[(((lo##i >> 16) & 7u) << 12) +                           \
                   (((lo##i >> 19) & 63u) << 6) + lane], w##i * xv##i);

__global__ __launch_bounds__(512) void rgcn_agg_kernel(
    const float* __restrict__ x,
    const float* __restrict__ blocks,
    const uint64* __restrict__ payload,
    const uint32* __restrict__ bbase,
    float* __restrict__ out,
    int num_nodes)
{
    __shared__ float agg[NREL * 64 * DIM];   // 128 KiB: agg[r][node][ch]
    __shared__ float blkT[LDS_T_TOTAL];      //  24 KiB: blkT[r][b][o][i] padded

    for (int l = threadIdx.x; l < NREL * NBLK * BS * BS; l += 512) {
        const int o = l & 7;
        const int i = (l >> 3) & 7;
        const int rb = l >> 6;
        blkT[(rb * 8 + o) * COL_PAD + i] = blocks[l];
    }
    float4* az = (float4*)agg;
    for (int i = threadIdx.x; i < NREL * 64 * DIM / 4; i += 512)
        az[i] = float4{0.f, 0.f, 0.f, 0.f};
    __syncthreads();

    const int lane = threadIdx.x & 63;
    const int wid  = __builtin_amdgcn_readfirstlane((int)threadIdx.x >> 6);
    const int b    = blockIdx.x;
    const int beg  = (int)bbase[b];
    const int end  = (int)bbase[b + 1];

    // -- phase 1: segment-sum into agg, 8 edges in flight per wave --
    int j = beg + wid;
    for (; j + 7 * NW < end; j += 8 * NW) {
        PREA(0, j)          PREA(1, j + NW)     PREA(2, j + 2 * NW)
        PREA(3, j + 3 * NW) PREA(4, j + 4 * NW) PREA(5, j + 5 * NW)
        PREA(6, j + 6 * NW) PREA(7, j + 7 * NW)
        EMITA(0) EMITA(1) EMITA(2) EMITA(3)
        EMITA(4) EMITA(5) EMITA(6) EMITA(7)
    }
    for (; j < end; j += NW) {
        PREA(0, j)
        EMITA(0)
    }
    __syncthreads();

    // -- phase 2: out[n][bb*8+oo] = sum_r dot(B_r col, agg[r][n][bb*8..]) --
    const int bb = lane >> 3;
    const int oo = lane & 7;
    const int n0 = b << 6;

    float accp[8] = {0.f, 0.f, 0.f, 0.f, 0.f, 0.f, 0.f, 0.f};
#pragma unroll
    for (int r = 0; r < NREL; ++r) {
        const float* cp = &blkT[((r * 8 + bb) * 8 + oo) * COL_PAD];
        const float4 c0 = *(const float4*)cp;
        const float4 c1 = *(const float4*)(cp + 4);
#pragma unroll
        for (int k = 0; k < 8; ++k) {
            const int n = wid * 8 + k;
            const float* ap = agg + (r << 12) + (n << 6) + (bb << 3);
            const float4 a0 = *(const float4*)ap;
            const float4 a1 = *(const float4*)(ap + 4);
            accp[k] += a0.x * c0.x + a0.y * c0.y + a0.z * c0.z + a0.w * c0.w
                     + a1.x * c1.x + a1.y * c1.y + a1.z * c1.z + a1.w * c1.w;
        }
    }
#pragma unroll
    for (int k = 0; k < 8; ++k) {
        const int gn = n0 + wid * 8 + k;
        if (gn < num_nodes) out[(size_t)gn * DIM + lane] = accp[k];
    }
}

// ---- Fallback (ws too small / nb too big): round-1 proven atomic kernel -----
#define LDS_BLK_STRIDE 72
#define LDS_REL_STRIDE (NBLK * LDS_BLK_STRIDE)
#define LDS_TOTAL (NREL * LDS_REL_STRIDE)

__global__ __launch_bounds__(256) void rgcn_edge_kernel(
    const float* __restrict__ x, const float* __restrict__ blocks,
    const float* __restrict__ ew, const int* __restrict__ src,
    const int* __restrict__ tgt, const int* __restrict__ etype,
    float* __restrict__ out, int num_edges)
{
    __shared__ float blk[LDS_TOTAL];
    for (int l = threadIdx.x; l < NREL * NBLK * BS * BS; l += blockDim.x) {
        int r = l >> 9, bb = (l >> 6) & 7, rest = l & 63;
        blk[r * LDS_REL_STRIDE + bb * LDS_BLK_STRIDE + rest] = blocks[l];
    }
    __syncthreads();
    const int lane = threadIdx.x & 63;
    const int wave = blockIdx.x * (blockDim.x >> 6) + (threadIdx.x >> 6);
    const int total_waves = gridDim.x * (blockDim.x >> 6);
    const int b = lane >> 3;
    for (int e = wave; e < num_edges; e += total_waves) {
        const int s = src[e], t = tgt[e], r = etype[e];
        const float w = ew[e];
        const float4* xs = reinterpret_cast<const float4*>(x + (size_t)s * DIM + b * BS);
        const float4 v0 = xs[0], v1 = xs[1];
        const float* bb = &blk[r * LDS_REL_STRIDE + b * LDS_BLK_STRIDE + (lane & 7)];
        float a = v0.x * bb[0] + v0.y * bb[BS] + v0.z * bb[2 * BS] + v0.w * bb[3 * BS]
                + v1.x * bb[4 * BS] + v1.y * bb[5 * BS] + v1.z * bb[6 * BS] + v1.w * bb[7 * BS];
        atomicAdd(&out[(size_t)t * DIM + lane], w * a);
    }
}

extern "C" void kernel_launch(void* const* d_in, const int* in_sizes, int n_in,
                              void* d_out, int out_size, void* d_ws, size_t ws_size,
                              hipStream_t stream) {
    const float* x      = (const float*)d_in[0];
    const float* blocks = (const float*)d_in[1];
    const float* ew     = (const float*)d_in[2];
    const int*   src    = (const int*)d_in[3];
    const int*   tgt    = (const int*)d_in[4];
    const int*   etype  = (const int*)d_in[5];
    float* out = (float*)d_out;

    const int num_edges = in_sizes[2];
    const int num_nodes = in_sizes[0] / DIM;

    const int nb = (num_nodes + 63) >> 6;           // 64-node buckets
    const int nt = (num_edges + TILE - 1) / TILE;   // sort tiles

    // ws: payload (E u64) | tile_hist (nt*nb u32) | totals (nb) | bbase (nb+1)
    const size_t payload_b = (size_t)num_edges * 8;
    const size_t th_b      = (size_t)nt * nb * 4;
    const size_t tot_b     = (size_t)nb * 4;
    const size_t bb_b      = (size_t)(nb + 1) * 4;
    const size_t need      = payload_b + th_b + tot_b + bb_b;

    if (nb > MAXB || ws_size < need) {   // fallback: round-1 atomic kernel
        hipMemsetAsync(d_out, 0, (size_t)out_size * sizeof(float), stream);
        rgcn_edge_kernel<<<2048, 256, 0, stream>>>(
            x, blocks, ew, src, tgt, etype, out, num_edges);
        return;
    }

    char* ws = (char*)d_ws;
    uint64* payload   = (uint64*)ws;
    uint32* tile_hist = (uint32*)(ws + payload_b);
    uint32* totals    = (uint32*)(ws + payload_b + th_b);
    uint32* bbase     = (uint32*)(ws + payload_b + th_b + tot_b);

    histA<<<nt, 512, 0, stream>>>(tgt, tile_hist, num_edges, nb);
    colscan<<<nb, 64, 0, stream>>>(tile_hist, totals, nt, nb);
    scan_totals<<<1, 512, 0, stream>>>(totals, bbase, nb);
    scatterB<<<nt, 512, 0, stream>>>(
        src, tgt, etype, ew, tile_hist, bbase, payload, num_edges, nb);
    rgcn_agg_kernel<<<nb, 512, 0, stream>>>(
        x, blocks, payload, bbase, out, num_nodes);
}

// Round 10
// 103.007 us; speedup vs baseline: 12.0978x; 5.2338x over previous
//
#include <hip/hip_runtime.h>

// RGCN block-decomposition: two-level counting sort (bucket, then within-
// bucket in LDS) + R4-proven chunked segmented-reduction consumer.
//
// Evidence trail: global-atomic path pinned at ~115us (R1/5/6/7, three
// layouts); plane-spread falsified (R8, write-amp); monolithic LDS agg
// falsified (R9, 1 block/CU). R4's chunk consumer measured 71us but its
// flat 50K-cursor scatter cost 70us in write-amp. This round keeps R9's
// cheap bucketed scatter (contiguous cursor runs) and adds a ~5us in-LDS
// within-bucket sort so the consumer sees a fully (bucket,tl)-sorted array.
//
//   1. histA:       per-4096-edge tile histogram of bucket = tgt>>6
//   2. colscan:     per-bucket exclusive prefix over tiles + totals
//   3. scan_totals: exclusive scan of bucket totals -> bbase[nb+1]
//   4. scatterB:    LDS-cursor scatter of {w|tl|r|s} u64 into bucket order
//   5. sortW:       per-bucket 64-counter counting sort in LDS (in place),
//                   writes keyt[] = global target id per slot
//   6. rgcn_chunk_kernel (R4): wave-per-64-edge chunk, ILP=4, register acc,
//                   row-atomic flush only at target boundaries

#define DIM 64
#define NBLK 8
#define BS 8
#define NREL 8
#define COL_PAD 12                                  // 8 -> 12 floats row pad
#define LDS_T_TOTAL (NREL * NBLK * BS * COL_PAD)    // 6144 floats = 24 KiB
#define CHUNK 64

#define TILE 4096      // edges per sort tile
#define MAXB 1024      // max buckets (LDS hist/cursor arrays)
#define SORTW_CAP 4096 // max edges staged per bucket in sortW (32 KiB)

typedef unsigned int uint32;
typedef unsigned long long uint64;
typedef unsigned short uint16;

// ---- 1. per-tile bucket histogram -------------------------------------------
__global__ __launch_bounds__(512) void histA(
    const int* __restrict__ tgt, uint32* __restrict__ tile_hist,
    int num_edges, int nb)
{
    __shared__ uint32 h[MAXB];
    for (int i = threadIdx.x; i < nb; i += 512) h[i] = 0u;
    __syncthreads();
    const int base = blockIdx.x * TILE;
    const int end  = min(base + TILE, num_edges);
    for (int j = base + (int)threadIdx.x; j < end; j += 512)
        atomicAdd(&h[tgt[j] >> 6], 1u);
    __syncthreads();
    uint32* dst = tile_hist + (size_t)blockIdx.x * nb;
    for (int i = threadIdx.x; i < nb; i += 512) dst[i] = h[i];
}

// ---- 2. per-bucket exclusive prefix over tiles (in place) + totals ----------
__global__ __launch_bounds__(64) void colscan(
    uint32* __restrict__ tile_hist, uint32* __restrict__ totals,
    int nt, int nb)
{
    const int b    = blockIdx.x;
    const int lane = threadIdx.x;
    uint32 carry = 0;
    for (int t0 = 0; t0 < nt; t0 += 64) {
        const int t = t0 + lane;
        uint32 v = (t < nt) ? tile_hist[(size_t)t * nb + b] : 0u;
        uint32 xin = v;
#pragma unroll
        for (int d = 1; d < 64; d <<= 1) {
            uint32 tm = __shfl_up(xin, d, 64);
            if (lane >= d) xin += tm;
        }
        if (t < nt) tile_hist[(size_t)t * nb + b] = carry + xin - v;
        carry += __shfl(xin, 63, 64);
    }
    if (lane == 0) totals[b] = carry;
}

// ---- 3. exclusive scan of bucket totals -> bbase[0..nb] ---------------------
__global__ __launch_bounds__(512) void scan_totals(
    const uint32* __restrict__ totals, uint32* __restrict__ bbase, int nb)
{
    __shared__ uint32 wtot[8];
    const int tid = threadIdx.x, lane = tid & 63, wid = tid >> 6;
    uint32 carry = 0;
    const int nch = (nb + 511) >> 9;
    for (int c = 0; c < nch; ++c) {
        const int idx = (c << 9) + tid;
        uint32 v = (idx < nb) ? totals[idx] : 0u;
        uint32 xin = v;
#pragma unroll
        for (int d = 1; d < 64; d <<= 1) {
            uint32 t = __shfl_up(xin, d, 64);
            if (lane >= d) xin += t;
        }
        if (lane == 63) wtot[wid] = xin;
        __syncthreads();
        if (wid == 0) {
            uint32 y = (lane < 8) ? wtot[lane] : 0u;
#pragma unroll
            for (int d = 1; d < 8; d <<= 1) {
                uint32 t = __shfl_up(y, d, 64);
                if (lane >= d) y += t;
            }
            if (lane < 8) wtot[lane] = y;
        }
        __syncthreads();
        const uint32 base = carry + ((wid > 0) ? wtot[wid - 1] : 0u);
        if (idx < nb) bbase[idx] = base + xin - v;
        carry += wtot[7];
        __syncthreads();
    }
    if (tid == 0) bbase[nb] = carry;
}

// ---- 4. scatter packed payloads into bucket-sorted order --------------------
__global__ __launch_bounds__(512) void scatterB(
    const int* __restrict__ src, const int* __restrict__ tgt,
    const int* __restrict__ etype, const float* __restrict__ ew,
    const uint32* __restrict__ tile_hist, const uint32* __restrict__ bbase,
    uint64* __restrict__ payload, int num_edges, int nb)
{
    __shared__ uint32 cur[MAXB];
    const uint32* th = tile_hist + (size_t)blockIdx.x * nb;
    for (int i = threadIdx.x; i < nb; i += 512) cur[i] = bbase[i] + th[i];
    __syncthreads();
    const int base = blockIdx.x * TILE;
    const int end  = min(base + TILE, num_edges);
    for (int j = base + (int)threadIdx.x; j < end; j += 512) {
        const int t = tgt[j];
        const uint32 pos = atomicAdd(&cur[t >> 6], 1u);
        // lo: s[0:15] | r[16:18] | tlocal[19:24]  (s<65536, r<8)
        const uint32 lo = (uint32)src[j] | ((uint32)etype[j] << 16)
                        | ((uint32)(t & 63) << 19);
        payload[pos] = ((uint64)__float_as_uint(ew[j]) << 32) | lo;
    }
}

// ---- 5. within-bucket counting sort (in place, LDS-staged) ------------------
__global__ __launch_bounds__(256) void sortW(
    uint64* __restrict__ payload, uint16* __restrict__ keyt,
    const uint32* __restrict__ bbase)
{
    __shared__ uint64 pay[SORTW_CAP];     // 32 KiB
    __shared__ uint32 hist[64];
    __shared__ uint32 cur[64];
    const int b   = blockIdx.x;
    const int beg = (int)bbase[b];
    const int cnt = (int)bbase[b + 1] - beg;

    if (cnt > SORTW_CAP) {   // oversized bucket: skip sort, just fill keys.
        for (int k = threadIdx.x; k < cnt; k += 256) {
            const uint32 lo = (uint32)payload[beg + k];
            keyt[beg + k] = (uint16)((b << 6) | ((lo >> 19) & 63u));
        }
        return;              // consumer stays correct (more flushes only)
    }

    for (int k = threadIdx.x; k < cnt; k += 256) pay[k] = payload[beg + k];
    if (threadIdx.x < 64) hist[threadIdx.x] = 0u;
    __syncthreads();
    for (int k = threadIdx.x; k < cnt; k += 256)
        atomicAdd(&hist[((uint32)pay[k] >> 19) & 63u], 1u);
    __syncthreads();
    if (threadIdx.x < 64) {   // wave 0: exclusive scan of the 64 counters
        const int lane = threadIdx.x;
        uint32 v = hist[lane], xin = v;
#pragma unroll
        for (int d = 1; d < 64; d <<= 1) {
            uint32 t = __shfl_up(xin, d, 64);
            if (lane >= d) xin += t;
        }
        cur[lane] = xin - v;
    }
    __syncthreads();
    for (int k = threadIdx.x; k < cnt; k += 256) {
        const uint64 p  = pay[k];
        const uint32 tl = ((uint32)p >> 19) & 63u;
        const uint32 pos = atomicAdd(&cur[tl], 1u);
        payload[beg + pos] = p;
        keyt[beg + pos] = (uint16)((b << 6) | tl);
    }
}

// ---- 6. chunked segmented reduction, ILP=4 (R4-proven, 71us) ----------------
#define PRE(i, p_)                                                          \
    const uint32 lo##i = (uint32)(p_);                                      \
    const float  w##i  = __uint_as_float((uint32)((p_) >> 32));             \
    const float* bp##i = bcol + ((lo##i >> 16) & 7) * (NBLK * BS * COL_PAD);\
    const float4 c0_##i = *(const float4*)bp##i;                            \
    const float4 c1_##i = *(const float4*)(bp##i + 4);                      \
    const float4* xs##i = (const float4*)(x + (size_t)(lo##i & 0xFFFF) * DIM + b * BS); \
    const float4 v0_##i = xs##i[0];                                         \
    const float4 v1_##i = xs##i[1];

#define ACC(i, t_)                                                          \
    {                                                                       \
        const int tt = (int)(t_);                                           \
        if (tt != tcur) {                                                   \
            atomicAdd(out + (size_t)tcur * DIM + lane, acc);                \
            acc = 0.0f; tcur = tt;                                          \
        }                                                                   \
        acc = fmaf(w##i,                                                    \
                   v0_##i.x * c0_##i.x + v0_##i.y * c0_##i.y +              \
                   v0_##i.z * c0_##i.z + v0_##i.w * c0_##i.w +              \
                   v1_##i.x * c1_##i.x + v1_##i.y * c1_##i.y +              \
                   v1_##i.z * c1_##i.z + v1_##i.w * c1_##i.w, acc);         \
    }

__global__ __launch_bounds__(512) void rgcn_chunk_kernel(
    const float* __restrict__ x,
    const float* __restrict__ blocks,
    const uint64* __restrict__ payload,
    const uint16* __restrict__ keyt,
    float* __restrict__ out,
    int num_edges)
{
    __shared__ float blkT[LDS_T_TOTAL];
    // blkT[((r*8+b)*8 + o)*12 + i] = blocks[r][b][i][o]; per-lane column read
    // is 2x ds_read_b128 at 48B stride -> 2 lanes/bank (0 conflicts measured).
    for (int l = threadIdx.x; l < NREL * NBLK * BS * BS; l += blockDim.x) {
        const int o = l & 7;
        const int i = (l >> 3) & 7;
        const int rb = l >> 6;
        blkT[(rb * 8 + o) * COL_PAD + i] = blocks[l];
    }
    __syncthreads();

    const int lane = threadIdx.x & 63;
    const int wid  = __builtin_amdgcn_readfirstlane(threadIdx.x >> 6);
    const int wave = blockIdx.x * (int)(blockDim.x >> 6) + wid;
    const int beg  = wave * CHUNK;
    if (beg >= num_edges) return;
    const int end  = min(beg + CHUNK, num_edges);

    const int b  = lane >> 3;
    const int oo = lane & 7;
    const float* bcol = &blkT[(b * 8 + oo) * COL_PAD];

    int   tcur = (int)keyt[beg];
    float acc  = 0.0f;

    int j = beg;
    for (; j + 4 <= end; j += 4) {
        const uint64 p0 = payload[j];
        const uint64 p1 = payload[j + 1];
        const uint64 p2 = payload[j + 2];
        const uint64 p3 = payload[j + 3];
        const ushort4 kk = *(const ushort4*)(keyt + j);   // j%4==0 -> aligned
        PRE(0, p0) PRE(1, p1) PRE(2, p2) PRE(3, p3)
        ACC(0, kk.x) ACC(1, kk.y) ACC(2, kk.z) ACC(3, kk.w)
    }
    for (; j < end; ++j) {                                // tail
        const uint64 p0 = payload[j];
        const uint16 k0 = keyt[j];
        PRE(0, p0)
        ACC(0, k0)
    }
    atomicAdd(out + (size_t)tcur * DIM + lane, acc);      // final flush
}

// ---- Fallback (ws too small / nb too big): round-1 proven atomic kernel -----
#define LDS_BLK_STRIDE 72
#define LDS_REL_STRIDE (NBLK * LDS_BLK_STRIDE)
#define LDS_TOTAL (NREL * LDS_REL_STRIDE)

__global__ __launch_bounds__(256) void rgcn_edge_kernel(
    const float* __restrict__ x, const float* __restrict__ blocks,
    const float* __restrict__ ew, const int* __restrict__ src,
    const int* __restrict__ tgt, const int* __restrict__ etype,
    float* __restrict__ out, int num_edges)
{
    __shared__ float blk[LDS_TOTAL];
    for (int l = threadIdx.x; l < NREL * NBLK * BS * BS; l += blockDim.x) {
        int r = l >> 9, bb = (l >> 6) & 7, rest = l & 63;
        blk[r * LDS_REL_STRIDE + bb * LDS_BLK_STRIDE + rest] = blocks[l];
    }
    __syncthreads();
    const int lane = threadIdx.x & 63;
    const int wave = blockIdx.x * (blockDim.x >> 6) + (threadIdx.x >> 6);
    const int total_waves = gridDim.x * (blockDim.x >> 6);
    const int b = lane >> 3;
    for (int e = wave; e < num_edges; e += total_waves) {
        const int s = src[e], t = tgt[e], r = etype[e];
        const float w = ew[e];
        const float4* xs = reinterpret_cast<const float4*>(x + (size_t)s * DIM + b * BS);
        const float4 v0 = xs[0], v1 = xs[1];
        const float* bb = &blk[r * LDS_REL_STRIDE + b * LDS_BLK_STRIDE + (lane & 7)];
        float a = v0.x * bb[0] + v0.y * bb[BS] + v0.z * bb[2 * BS] + v0.w * bb[3 * BS]
                + v1.x * bb[4 * BS] + v1.y * bb[5 * BS] + v1.z * bb[6 * BS] + v1.w * bb[7 * BS];
        atomicAdd(&out[(size_t)t * DIM + lane], w * a);
    }
}

extern "C" void kernel_launch(void* const* d_in, const int* in_sizes, int n_in,
                              void* d_out, int out_size, void* d_ws, size_t ws_size,
                              hipStream_t stream) {
    const float* x      = (const float*)d_in[0];
    const float* blocks = (const float*)d_in[1];
    const float* ew     = (const float*)d_in[2];
    const int*   src    = (const int*)d_in[3];
    const int*   tgt    = (const int*)d_in[4];
    const int*   etype  = (const int*)d_in[5];
    float* out = (float*)d_out;

    const int num_edges = in_sizes[2];
    const int num_nodes = in_sizes[0] / DIM;

    const int nb = (num_nodes + 63) >> 6;           // 64-node buckets
    const int nt = (num_edges + TILE - 1) / TILE;   // sort tiles

    // ws: payload (E u64) | keyt (E u16) | tile_hist (nt*nb u32)
    //   | totals (nb u32) | bbase (nb+1 u32)
    const size_t payload_b = (size_t)num_edges * 8;
    const size_t keyt_b    = (size_t)num_edges * 2;
    const size_t th_b      = (size_t)nt * nb * 4;
    const size_t tot_b     = (size_t)nb * 4;
    const size_t bb_b      = (size_t)(nb + 1) * 4;
    const size_t need      = payload_b + keyt_b + th_b + tot_b + bb_b;

    if (nb > MAXB || ws_size < need) {   // fallback: round-1 atomic kernel
        hipMemsetAsync(d_out, 0, (size_t)out_size * sizeof(float), stream);
        rgcn_edge_kernel<<<2048, 256, 0, stream>>>(
            x, blocks, ew, src, tgt, etype, out, num_edges);
        return;
    }

    char* ws = (char*)d_ws;
    uint64* payload   = (uint64*)ws;
    uint16* keyt      = (uint16*)(ws + payload_b);
    uint32* tile_hist = (uint32*)(ws + payload_b + keyt_b);
    uint32* totals    = (uint32*)(ws + payload_b + keyt_b + th_b);
    uint32* bbase     = (uint32*)(ws + payload_b + keyt_b + th_b + tot_b);

    hipMemsetAsync(d_out, 0, (size_t)out_size * sizeof(float), stream);
    histA<<<nt, 512, 0, stream>>>(tgt, tile_hist, num_edges, nb);
    colscan<<<nb, 64, 0, stream>>>(tile_hist, totals, nt, nb);
    scan_totals<<<1, 512, 0, stream>>>(totals, bbase, nb);
    scatterB<<<nt, 512, 0, stream>>>(
        src, tgt, etype, ew, tile_hist, bbase, payload, num_edges, nb);
    sortW<<<nb, 256, 0, stream>>>(payload, keyt, bbase);

    const int waves   = (num_edges + CHUNK - 1) / CHUNK;
    const int gblocks = (waves + 7) / 8;
    rgcn_chunk_kernel<<<gblocks, 512, 0, stream>>>(
        x, blocks, payload, keyt, out, num_edges);
}